// Round 5
// baseline (287.669 us; speedup 1.0000x reference)
//
#include <hip/hip_runtime.h>
#include <hip/hip_bf16.h>
#include <math.h>

#define B_ 2
#define T_ 2048
#define D_ 1024
#define H_ 16
#define HD 64

typedef __bf16 bf16;
typedef bf16 bf16x8 __attribute__((ext_vector_type(8)));
typedef bf16 bf16x4 __attribute__((ext_vector_type(4)));
typedef short short4v __attribute__((ext_vector_type(4)));
typedef float f32x4 __attribute__((ext_vector_type(4)));

// async global->LDS, 16B per lane. LDS dest must be wave-uniform base + lane*16 (m104/m108).
#define GL2LDS16(g, l) __builtin_amdgcn_global_load_lds(                      \
    (const __attribute__((address_space(1))) void*)(g),                       \
    (__attribute__((address_space(3))) void*)(l), 16, 0, 0)

// 16x16x16 bf16 MFMA (K=16): gfx90a-era builtin name; guarded from the host pass.
static __device__ __forceinline__ f32x4 mfma16x16x16(bf16x4 a, bf16x4 b, f32x4 c) {
#if defined(__HIP_DEVICE_COMPILE__)
# if __has_builtin(__builtin_amdgcn_mfma_f32_16x16x16bf16_1k)
    return __builtin_amdgcn_mfma_f32_16x16x16bf16_1k(
        __builtin_bit_cast(short4v, a), __builtin_bit_cast(short4v, b), c, 0, 0, 0);
# else
    asm("v_mfma_f32_16x16x16_bf16 %0, %1, %2, %0" : "+v"(c) : "v"(a), "v"(b));
    return c;
# endif
#else
    (void)a; (void)b;
    return c;
#endif
}

// ---------------------------------------------------------------- cast x->bf16
__global__ __launch_bounds__(256) void cast_f32_bf16(const float* __restrict__ in,
                                                     bf16* __restrict__ out, int n) {
    int i = (blockIdx.x * 256 + threadIdx.x) * 4;
    if (i + 3 < n) {
        float4 v = *(const float4*)(in + i);
        bf16 tmp[4] = {(bf16)v.x, (bf16)v.y, (bf16)v.z, (bf16)v.w};
        *(uint2*)(out + i) = *(const uint2*)tmp;
    }
}

// --------------------------- W[k][n] f32 -> Wt[z][n][k] bf16, all 4 weights in one launch
__global__ __launch_bounds__(256) void transpose_cast4(const float* __restrict__ W0,
                                                       const float* __restrict__ W1,
                                                       const float* __restrict__ W2,
                                                       const float* __restrict__ W3,
                                                       bf16* __restrict__ Wt) {
    __shared__ bf16 tile[64 * 72];
    const int z = blockIdx.z;
    const float* W = (z == 0) ? W0 : (z == 1) ? W1 : (z == 2) ? W2 : W3;
    bf16* out = Wt + (size_t)z * D_ * D_;
    const int k0 = blockIdx.y * 64, n0 = blockIdx.x * 64;
    const int tid = threadIdx.x;
    for (int it = 0; it < 4; ++it) {
        int idx = it * 256 + tid;
        int r = idx >> 4;                // k row
        int c4 = (idx & 15) << 2;        // n col
        float4 v = *(const float4*)(W + (size_t)(k0 + r) * D_ + n0 + c4);
        tile[(c4 + 0) * 72 + r] = (bf16)v.x;
        tile[(c4 + 1) * 72 + r] = (bf16)v.y;
        tile[(c4 + 2) * 72 + r] = (bf16)v.z;
        tile[(c4 + 3) * 72 + r] = (bf16)v.w;
    }
    __syncthreads();
    for (int it = 0; it < 2; ++it) {
        int idx = it * 256 + tid;
        int r = idx >> 3;                // n row
        int c8 = (idx & 7) << 3;         // k col
        bf16x8 v = *(const bf16x8*)&tile[r * 72 + c8];
        *(bf16x8*)(out + (size_t)(n0 + r) * D_ + k0 + c8) = v;
    }
}

// ---------------------------------------------------------------- MFMA GEMM (m97-style)
// C[M,N] = A[M,K] @ Bt[N,K]^T.  BM=BN=128, BK=32, 256 thr = 4 waves, each 64x64.
// Staging via global_load_lds dwordx4 into UNPADDED [128][32] LDS (lane-contiguous).
// mode 0: out bf16; z=0(Q),1(K) -> [B,H,T,hd]; z=2(V) -> [B,H,hd,T] (transposed)
// mode 1: out fp32 row-major
__global__ __launch_bounds__(256) void gemm_bf16(const bf16* __restrict__ A,
                                                 const bf16* __restrict__ Bt,
                                                 void* __restrict__ Cout,
                                                 int M, int N, int K, int mode) {
    __shared__ bf16 As[128 * 32];
    __shared__ bf16 Bs[128 * 32];
    const int tid = threadIdx.x;
    const int wave = tid >> 6, lane = tid & 63;
    const int quad = lane >> 4, l16 = lane & 15;
    const int wr = wave >> 1, wc = wave & 1;
    const int m0 = blockIdx.y * 128, n0 = blockIdx.x * 128;
    const int z = blockIdx.z;
    const bf16* Bz = Bt + (size_t)z * N * K;

    // staging addresses: wave w covers rows [w*32, w*32+32); lane l -> row w*32+j*16+(l>>2),
    // chunk (l&3)*8 elems. LDS dest = base + lane*16 bytes (contiguous, required).
    const int lrow = lane >> 2, lcol = (lane & 3) << 3;
    const bf16* ag = A  + (size_t)(m0 + wave * 32 + lrow) * K + lcol;
    const bf16* bg = Bz + (size_t)(n0 + wave * 32 + lrow) * K + lcol;
    bf16* asl = &As[(wave * 32 + lrow) * 32 + lcol];
    bf16* bsl = &Bs[(wave * 32 + lrow) * 32 + lcol];

    f32x4 acc[4][4];
    for (int mi = 0; mi < 4; ++mi)
        for (int ni = 0; ni < 4; ++ni) acc[mi][ni] = (f32x4){0.f, 0.f, 0.f, 0.f};

    for (int kb = 0; kb < K; kb += 32) {
        GL2LDS16(ag + kb, asl);
        GL2LDS16(ag + (size_t)16 * K + kb, asl + 16 * 32);
        GL2LDS16(bg + kb, bsl);
        GL2LDS16(bg + (size_t)16 * K + kb, bsl + 16 * 32);
        __syncthreads();   // drains vmcnt -> LDS writes visible
        bf16x8 af[4], bfr[4];
        for (int mi = 0; mi < 4; ++mi)
            af[mi] = *(const bf16x8*)&As[(wr * 64 + mi * 16 + l16) * 32 + quad * 8];
        for (int ni = 0; ni < 4; ++ni)
            bfr[ni] = *(const bf16x8*)&Bs[(wc * 64 + ni * 16 + l16) * 32 + quad * 8];
        for (int mi = 0; mi < 4; ++mi)
            for (int ni = 0; ni < 4; ++ni)
                acc[mi][ni] = __builtin_amdgcn_mfma_f32_16x16x32_bf16(af[mi], bfr[ni],
                                                                      acc[mi][ni], 0, 0, 0);
        __syncthreads();
    }

    // C/D layout: col = lane&15, row = quad*4 + reg
    if (mode == 0) {
        bf16* Cb = (bf16*)Cout + (size_t)z * M * N;
        for (int mi = 0; mi < 4; ++mi)
            for (int ni = 0; ni < 4; ++ni)
                for (int r = 0; r < 4; ++r) {
                    int m = m0 + wr * 64 + mi * 16 + quad * 4 + r;
                    int n = n0 + wc * 64 + ni * 16 + l16;
                    int b = m >> 11, t = m & (T_ - 1);
                    int h = n >> 6, d = n & (HD - 1);
                    size_t idx = (z == 2)
                        ? ((((size_t)b * H_ + h) * HD + d) * T_ + t)        // V^T [B,H,hd,T]
                        : (((((size_t)b * H_ + h) * T_ + t) << 6) + d);     // [B,H,T,hd]
                    Cb[idx] = (bf16)acc[mi][ni][r];
                }
    } else {
        float* Cf = (float*)Cout;
        for (int mi = 0; mi < 4; ++mi)
            for (int ni = 0; ni < 4; ++ni)
                for (int r = 0; r < 4; ++r) {
                    int m = m0 + wr * 64 + mi * 16 + quad * 4 + r;
                    int n = n0 + wc * 64 + ni * 16 + l16;
                    Cf[(size_t)m * N + n] = acc[mi][ni][r];
                }
    }
}

// ---------------------------------------------------------------- flash attention (S^T, paired tiles)
// Q,K: [B,H,T,hd] bf16.  Vt: [B,H,hd,T] bf16.  Out: [B,T,H,hd] bf16.
// Block p handles q-tiles {p, 31-p} (64 rows each): nktA+nktB == 17 for all p -> uniform cost.
// Both tiles consume the same staged K/V tile. Register prefetch of tile kt+1 overlaps compute.
#define LDK 72
#define LDP 136

__global__ __launch_bounds__(256, 2) void attn_kernel(const bf16* __restrict__ Q,
                                                      const bf16* __restrict__ K,
                                                      const bf16* __restrict__ Vt,
                                                      bf16* __restrict__ O) {
    __shared__ bf16 Ks[128 * LDK];  // [key][dim]
    __shared__ bf16 Vs[64 * LDP];   // [dim][key]

    const int p = blockIdx.x;                  // 0..15
    const int bh = blockIdx.y;                 // 0..31
    const int h = bh & (H_ - 1), b = bh >> 4;
    const int tid = threadIdx.x;
    const int wave = tid >> 6, lane = tid & 63;
    const int quad = lane >> 4, l16 = lane & 15;

    const bf16* Qb = Q + (size_t)bh * T_ * HD;
    const bf16* Kb = K + (size_t)bh * T_ * HD;
    const bf16* Vb = Vt + (size_t)bh * HD * T_;   // [hd][T]

    const float LOG2E = 1.44269504f;
    const float slope2 = exp2f(-0.5f * (float)(h + 1)) * LOG2E;
    const float c1 = 0.125f * LOG2E;

    const int qtA = p, qtB = 31 - p;
    const int nktA = (qtA >> 1) + 1;           // 128-key tiles for tile A
    const int nktB = (qtB >> 1) + 1;           // >= nktA

    // Q fragments for both tiles (B-operand layout of 16x16x32: n=l16, k=quad*8+j)
    bf16x8 qfA[2], qfB[2];
    {
        const bf16* qa = Qb + (size_t)(qtA * 64 + wave * 16 + l16) * HD + quad * 8;
        qfA[0] = *(const bf16x8*)(qa);
        qfA[1] = *(const bf16x8*)(qa + 32);
        const bf16* qb = Qb + (size_t)(qtB * 64 + wave * 16 + l16) * HD + quad * 8;
        qfB[0] = *(const bf16x8*)(qb);
        qfB[1] = *(const bf16x8*)(qb + 32);
    }

    f32x4 accA[4], accB[4];
    for (int df = 0; df < 4; ++df) {
        accA[df] = (f32x4){0.f, 0.f, 0.f, 0.f};
        accB[df] = (f32x4){0.f, 0.f, 0.f, 0.f};
    }
    float mA = -INFINITY, lA = 0.f, mB = -INFINITY, lB = 0.f;
    const int qglobA = qtA * 64 + wave * 16 + l16;
    const int qglobB = qtB * 64 + wave * 16 + l16;

    // staging: per thread 4 chunks of K (128x64) + 4 chunks of V (64x128), 16B each
    auto load_tile = [&](int kt, bf16x8 (&kr)[4], bf16x8 (&vr)[4]) {
        for (int c = 0; c < 4; ++c) {
            int idx = c * 256 + tid;
            kr[c] = *(const bf16x8*)(Kb + ((size_t)kt * 128 + (idx >> 3)) * HD + ((idx & 7) << 3));
            vr[c] = *(const bf16x8*)(Vb + (size_t)(idx >> 4) * T_ + kt * 128 + ((idx & 15) << 3));
        }
    };
    auto write_tile = [&](const bf16x8 (&kr)[4], const bf16x8 (&vr)[4]) {
        for (int c = 0; c < 4; ++c) {
            int idx = c * 256 + tid;
            *(bf16x8*)&Ks[(idx >> 3) * LDK + ((idx & 7) << 3)] = kr[c];
            *(bf16x8*)&Vs[(idx >> 4) * LDP + ((idx & 15) << 3)] = vr[c];
        }
    };

    // one softmax+PV step for one q-tile against the staged 128-key tile
    auto process = [&](const bf16x8 (&qf)[2], f32x4 (&acc)[4], float& m_run, float& l_run,
                       int qglob, bool lastt, int kt) {
        f32x4 s[8];
        for (int nf = 0; nf < 8; ++nf) {
            bf16x8 kf0 = *(const bf16x8*)&Ks[(nf * 16 + l16) * LDK + quad * 8];
            bf16x8 kf1 = *(const bf16x8*)&Ks[(nf * 16 + l16) * LDK + 32 + quad * 8];
            f32x4 zz = (f32x4){0.f, 0.f, 0.f, 0.f};
            zz = __builtin_amdgcn_mfma_f32_16x16x32_bf16(kf0, qf[0], zz, 0, 0, 0);
            zz = __builtin_amdgcn_mfma_f32_16x16x32_bf16(kf1, qf[1], zz, 0, 0, 0);
            s[nf] = zz;
        }
        const int jbase = kt * 128 + quad * 4;
        for (int nf = 0; nf < 8; ++nf)
            for (int r = 0; r < 4; ++r) {
                int j = jbase + nf * 16 + r;
                s[nf][r] = s[nf][r] * c1 + slope2 * (float)(j - (T_ - 1));
            }
        if (lastt) {
            for (int nf = 0; nf < 8; ++nf)
                for (int r = 0; r < 4; ++r)
                    if (jbase + nf * 16 + r > qglob) s[nf][r] = -INFINITY;
        }
        float mx = -INFINITY;
        for (int nf = 0; nf < 8; ++nf) {
            float a = fmaxf(fmaxf(s[nf][0], s[nf][1]), fmaxf(s[nf][2], s[nf][3]));
            mx = fmaxf(mx, a);
        }
        mx = fmaxf(mx, __shfl_xor(mx, 16, 64));
        mx = fmaxf(mx, __shfl_xor(mx, 32, 64));
        const float mnew = fmaxf(m_run, mx);
        const float alpha = exp2f(m_run - mnew);
        m_run = mnew;

        float rs = 0.f;
        bf16x4 pf[8];
        for (int nf = 0; nf < 8; ++nf) {
            float p0 = exp2f(s[nf][0] - mnew);
            float p1 = exp2f(s[nf][1] - mnew);
            float p2 = exp2f(s[nf][2] - mnew);
            float p3 = exp2f(s[nf][3] - mnew);
            rs += (p0 + p1) + (p2 + p3);
            pf[nf] = (bf16x4){(bf16)p0, (bf16)p1, (bf16)p2, (bf16)p3};
        }
        rs += __shfl_xor(rs, 16, 64);
        rs += __shfl_xor(rs, 32, 64);
        l_run = l_run * alpha + rs;
        for (int df = 0; df < 4; ++df) acc[df] *= alpha;

        for (int nf = 0; nf < 8; ++nf)
            for (int df = 0; df < 4; ++df) {
                bf16x4 vf = *(const bf16x4*)&Vs[(df * 16 + l16) * LDP + nf * 16 + quad * 4];
                acc[df] = mfma16x16x16(vf, pf[nf], acc[df]);
            }
    };

    {   // prologue: stage tile 0
        bf16x8 kr[4], vr[4];
        load_tile(0, kr, vr);
        write_tile(kr, vr);
    }
    __syncthreads();

    for (int kt = 0; kt < nktB; ++kt) {
        const bool more = (kt + 1 < nktB);
        bf16x8 kr[4], vr[4];
        if (more) load_tile(kt + 1, kr, vr);   // global latency overlaps compute below

        process(qfB, accB, mB, lB, qglobB, kt == nktB - 1, kt);
        if (kt < nktA)
            process(qfA, accA, mA, lA, qglobA, kt == nktA - 1, kt);

        if (more) {
            __syncthreads();                   // all waves done reading Ks/Vs
            write_tile(kr, vr);
            __syncthreads();
        }
    }

    // epilogue: O[b,t,h,d], d = df*16+quad*4+r (8B stores), for both tiles
    const float invA = 1.0f / lA, invB = 1.0f / lB;
    for (int df = 0; df < 4; ++df) {
        bf16 oA[4], oB[4];
        for (int r = 0; r < 4; ++r) {
            oA[r] = (bf16)(accA[df][r] * invA);
            oB[r] = (bf16)(accB[df][r] * invB);
        }
        *(uint2*)&O[(((size_t)b * T_ + qglobA) * H_ + h) * HD + df * 16 + quad * 4] =
            *(const uint2*)oA;
        *(uint2*)&O[(((size_t)b * T_ + qglobB) * H_ + h) * HD + df * 16 + quad * 4] =
            *(const uint2*)oB;
    }
}

// ---------------------------------------------------------------- launch
extern "C" void kernel_launch(void* const* d_in, const int* in_sizes, int n_in,
                              void* d_out, int out_size, void* d_ws, size_t ws_size,
                              hipStream_t stream) {
    const float* x  = (const float*)d_in[0];
    const float* Wq = (const float*)d_in[1];
    const float* Wk = (const float*)d_in[2];
    const float* Wv = (const float*)d_in[3];
    const float* Wo = (const float*)d_in[4];
    float* out = (float*)d_out;

    const size_t M = (size_t)B_ * T_;        // 4096
    const size_t XE = M * D_;                // 4 Mi elems
    const size_t WE = (size_t)D_ * D_;       // 1 Mi elems

    char* ws = (char*)d_ws;
    size_t off = 0;
    auto carve = [&](size_t bytes) {
        void* p = ws + off;
        off += (bytes + 255) & ~(size_t)255;
        return p;
    };
    bf16* xb  = (bf16*)carve(XE * 2);        // x bf16; reused as attn_out later
    bf16* Wt  = (bf16*)carve(4 * WE * 2);    // Wq,Wk,Wv,Wo transposed [N][K]
    bf16* QKV = (bf16*)carve(3 * XE * 2);    // Q,K [B,H,T,hd]; V [B,H,hd,T]
    bf16* attn = xb;  // safe: xb fully consumed by QKV gemm before attn_kernel runs

    cast_f32_bf16<<<dim3(XE / (4 * 256)), dim3(256), 0, stream>>>(x, xb, (int)XE);
    transpose_cast4<<<dim3(16, 16, 4), 256, 0, stream>>>(Wq, Wk, Wv, Wo, Wt);

    gemm_bf16<<<dim3(D_ / 128, M / 128, 3), 256, 0, stream>>>(xb, Wt, QKV,
                                                              (int)M, D_, D_, 0);
    attn_kernel<<<dim3(16, B_ * H_), 256, 0, stream>>>(QKV, QKV + XE, QKV + 2 * XE, attn);
    gemm_bf16<<<dim3(D_ / 128, M / 128, 1), 256, 0, stream>>>(attn, Wt + 3 * WE, out,
                                                              (int)M, D_, D_, 1);
}

// Round 6
// 243.973 us; speedup vs baseline: 1.1791x; 1.1791x over previous
//
#include <hip/hip_runtime.h>
#include <hip/hip_bf16.h>
#include <math.h>

#define B_ 2
#define T_ 2048
#define D_ 1024
#define H_ 16
#define HD 64

typedef __bf16 bf16;
typedef bf16 bf16x8 __attribute__((ext_vector_type(8)));
typedef bf16 bf16x4 __attribute__((ext_vector_type(4)));
typedef short short4v __attribute__((ext_vector_type(4)));
typedef float f32x4 __attribute__((ext_vector_type(4)));

// async global->LDS, 16B per lane. LDS dest must be wave-uniform base + lane*16 (m104/m108).
#define GL2LDS16(g, l) __builtin_amdgcn_global_load_lds(                      \
    (const __attribute__((address_space(1))) void*)(g),                       \
    (__attribute__((address_space(3))) void*)(l), 16, 0, 0)

// 16x16x16 bf16 MFMA (K=16): gfx90a-era builtin name; guarded from the host pass.
static __device__ __forceinline__ f32x4 mfma16x16x16(bf16x4 a, bf16x4 b, f32x4 c) {
#if defined(__HIP_DEVICE_COMPILE__)
# if __has_builtin(__builtin_amdgcn_mfma_f32_16x16x16bf16_1k)
    return __builtin_amdgcn_mfma_f32_16x16x16bf16_1k(
        __builtin_bit_cast(short4v, a), __builtin_bit_cast(short4v, b), c, 0, 0, 0);
# else
    asm("v_mfma_f32_16x16x16_bf16 %0, %1, %2, %0" : "+v"(c) : "v"(a), "v"(b));
    return c;
# endif
#else
    (void)a; (void)b;
    return c;
#endif
}

// ---------------------------------------------------------------- cast x->bf16
__global__ __launch_bounds__(256) void cast_f32_bf16(const float* __restrict__ in,
                                                     bf16* __restrict__ out, int n) {
    int i = (blockIdx.x * 256 + threadIdx.x) * 4;
    if (i + 3 < n) {
        float4 v = *(const float4*)(in + i);
        bf16 tmp[4] = {(bf16)v.x, (bf16)v.y, (bf16)v.z, (bf16)v.w};
        *(uint2*)(out + i) = *(const uint2*)tmp;
    }
}

// --------------------------- W[k][n] f32 -> Wt[z][n][k] bf16, all 4 weights in one launch
__global__ __launch_bounds__(256) void transpose_cast4(const float* __restrict__ W0,
                                                       const float* __restrict__ W1,
                                                       const float* __restrict__ W2,
                                                       const float* __restrict__ W3,
                                                       bf16* __restrict__ Wt) {
    __shared__ bf16 tile[64 * 72];
    const int z = blockIdx.z;
    const float* W = (z == 0) ? W0 : (z == 1) ? W1 : (z == 2) ? W2 : W3;
    bf16* out = Wt + (size_t)z * D_ * D_;
    const int k0 = blockIdx.y * 64, n0 = blockIdx.x * 64;
    const int tid = threadIdx.x;
    for (int it = 0; it < 4; ++it) {
        int idx = it * 256 + tid;
        int r = idx >> 4;                // k row
        int c4 = (idx & 15) << 2;        // n col
        float4 v = *(const float4*)(W + (size_t)(k0 + r) * D_ + n0 + c4);
        tile[(c4 + 0) * 72 + r] = (bf16)v.x;
        tile[(c4 + 1) * 72 + r] = (bf16)v.y;
        tile[(c4 + 2) * 72 + r] = (bf16)v.z;
        tile[(c4 + 3) * 72 + r] = (bf16)v.w;
    }
    __syncthreads();
    for (int it = 0; it < 2; ++it) {
        int idx = it * 256 + tid;
        int r = idx >> 3;                // n row
        int c8 = (idx & 7) << 3;         // k col
        bf16x8 v = *(const bf16x8*)&tile[r * 72 + c8];
        *(bf16x8*)(out + (size_t)(n0 + r) * D_ + k0 + c8) = v;
    }
}

// ---------------------------------------------------------------- MFMA GEMM (m97-style)
// C[M,N] = A[M,K] @ Bt[N,K]^T.  BM=BN=128, BK=32, 256 thr = 4 waves, each 64x64.
// Staging via global_load_lds dwordx4 into UNPADDED [128][32] LDS (lane-contiguous).
// mode 0: out bf16; z=0(Q),1(K) -> [B,H,T,hd]; z=2(V) -> [B,H,hd,T] (transposed)
// mode 1: out fp32 row-major
__global__ __launch_bounds__(256) void gemm_bf16(const bf16* __restrict__ A,
                                                 const bf16* __restrict__ Bt,
                                                 void* __restrict__ Cout,
                                                 int M, int N, int K, int mode) {
    __shared__ bf16 As[128 * 32];
    __shared__ bf16 Bs[128 * 32];
    const int tid = threadIdx.x;
    const int wave = tid >> 6, lane = tid & 63;
    const int quad = lane >> 4, l16 = lane & 15;
    const int wr = wave >> 1, wc = wave & 1;
    const int m0 = blockIdx.y * 128, n0 = blockIdx.x * 128;
    const int z = blockIdx.z;
    const bf16* Bz = Bt + (size_t)z * N * K;

    // wave w stages rows [w*32, w*32+32); lane l -> row w*32+(l>>2), chunk (l&3)*8 elems.
    // LDS dest = wave-uniform base + lane*16B (required by HW).
    const int lrow = lane >> 2, lcol = (lane & 3) << 3;
    const bf16* ag = A  + (size_t)(m0 + wave * 32 + lrow) * K + lcol;
    const bf16* bg = Bz + (size_t)(n0 + wave * 32 + lrow) * K + lcol;
    bf16* asl = &As[(wave * 32 + lrow) * 32 + lcol];
    bf16* bsl = &Bs[(wave * 32 + lrow) * 32 + lcol];

    f32x4 acc[4][4];
    for (int mi = 0; mi < 4; ++mi)
        for (int ni = 0; ni < 4; ++ni) acc[mi][ni] = (f32x4){0.f, 0.f, 0.f, 0.f};

    for (int kb = 0; kb < K; kb += 32) {
        GL2LDS16(ag + kb, asl);
        GL2LDS16(ag + (size_t)16 * K + kb, asl + 16 * 32);
        GL2LDS16(bg + kb, bsl);
        GL2LDS16(bg + (size_t)16 * K + kb, bsl + 16 * 32);
        __syncthreads();   // drains vmcnt -> LDS writes visible
        bf16x8 af[4], bfr[4];
        for (int mi = 0; mi < 4; ++mi)
            af[mi] = *(const bf16x8*)&As[(wr * 64 + mi * 16 + l16) * 32 + quad * 8];
        for (int ni = 0; ni < 4; ++ni)
            bfr[ni] = *(const bf16x8*)&Bs[(wc * 64 + ni * 16 + l16) * 32 + quad * 8];
        for (int mi = 0; mi < 4; ++mi)
            for (int ni = 0; ni < 4; ++ni)
                acc[mi][ni] = __builtin_amdgcn_mfma_f32_16x16x32_bf16(af[mi], bfr[ni],
                                                                      acc[mi][ni], 0, 0, 0);
        __syncthreads();
    }

    // C/D layout: col = lane&15, row = quad*4 + reg
    if (mode == 0) {
        bf16* Cb = (bf16*)Cout + (size_t)z * M * N;
        for (int mi = 0; mi < 4; ++mi)
            for (int ni = 0; ni < 4; ++ni)
                for (int r = 0; r < 4; ++r) {
                    int m = m0 + wr * 64 + mi * 16 + quad * 4 + r;
                    int n = n0 + wc * 64 + ni * 16 + l16;
                    int b = m >> 11, t = m & (T_ - 1);
                    int h = n >> 6, d = n & (HD - 1);
                    size_t idx = (z == 2)
                        ? ((((size_t)b * H_ + h) * HD + d) * T_ + t)        // V^T [B,H,hd,T]
                        : (((((size_t)b * H_ + h) * T_ + t) << 6) + d);     // [B,H,T,hd]
                    Cb[idx] = (bf16)acc[mi][ni][r];
                }
    } else {
        float* Cf = (float*)Cout;
        for (int mi = 0; mi < 4; ++mi)
            for (int ni = 0; ni < 4; ++ni)
                for (int r = 0; r < 4; ++r) {
                    int m = m0 + wr * 64 + mi * 16 + quad * 4 + r;
                    int n = n0 + wc * 64 + ni * 16 + l16;
                    Cf[(size_t)m * N + n] = acc[mi][ni][r];
                }
    }
}

// ---------------------------------------------------------------- flash attention (S^T form)
// Round-4 kernel, verbatim (proven 89.5 us, VGPR 64, 4 blocks/CU).
// Q,K: [B,H,T,hd] bf16.  Vt: [B,H,hd,T] bf16.  Out: [B,T,H,hd] bf16.
// S^T = K*Q^T via mfma(A=K,B=Q): C-layout key=quad*4+r, query=l16 == B-operand layout
// of 16x16x16 MFMA -> P feeds PV straight from registers.
#define LDK 72
#define LDP 136

__global__ __launch_bounds__(256, 4) void attn_kernel(const bf16* __restrict__ Q,
                                                      const bf16* __restrict__ K,
                                                      const bf16* __restrict__ Vt,
                                                      bf16* __restrict__ O) {
    __shared__ bf16 Ks[128 * LDK];  // [key][dim]
    __shared__ bf16 Vs[64 * LDP];   // [dim][key]

    const int bx = blockIdx.x, by = blockIdx.y;
    const int qt = 31 - ((bx + by) & 31);      // diagonal shuffle for load balance
    const int bh = by;
    const int h = bh & (H_ - 1), b = bh >> 4;
    const int tid = threadIdx.x;
    const int wave = tid >> 6, lane = tid & 63;
    const int quad = lane >> 4, l16 = lane & 15;

    const bf16* Qb = Q + (size_t)bh * T_ * HD;
    const bf16* Kb = K + (size_t)bh * T_ * HD;
    const bf16* Vb = Vt + (size_t)bh * HD * T_;   // [hd][T]

    const float LOG2E = 1.44269504f;
    const float slope2 = exp2f(-0.5f * (float)(h + 1)) * LOG2E;
    const float c1 = 0.125f * LOG2E;

    bf16x8 qf[2];
    {
        const bf16* qrow = Qb + (size_t)(qt * 64 + wave * 16 + l16) * HD + quad * 8;
        qf[0] = *(const bf16x8*)(qrow);
        qf[1] = *(const bf16x8*)(qrow + 32);
    }

    f32x4 acc[4];                    // O^T: d = df*16+quad*4+r, query = l16
    for (int df = 0; df < 4; ++df) acc[df] = (f32x4){0.f, 0.f, 0.f, 0.f};
    float m_run = -INFINITY, l_run = 0.f;

    const int qglob = qt * 64 + wave * 16 + l16;
    const int nkt = (qt >> 1) + 1;

    for (int kt = 0; kt < nkt; ++kt) {
        const bool last = (kt == nkt - 1);
        __syncthreads();
        for (int it = 0; it < 4; ++it) {
            int idx = it * 256 + tid;
            int rk = idx >> 3, ck = (idx & 7) << 3;
            *(bf16x8*)&Ks[rk * LDK + ck] =
                *(const bf16x8*)(Kb + (size_t)(kt * 128 + rk) * HD + ck);
            int rv = idx >> 4, cv = (idx & 15) << 3;
            *(bf16x8*)&Vs[rv * LDP + cv] =
                *(const bf16x8*)(Vb + (size_t)rv * T_ + kt * 128 + cv);
        }
        __syncthreads();

        f32x4 s[8];
        for (int nf = 0; nf < 8; ++nf) {
            bf16x8 kf0 = *(const bf16x8*)&Ks[(nf * 16 + l16) * LDK + quad * 8];
            bf16x8 kf1 = *(const bf16x8*)&Ks[(nf * 16 + l16) * LDK + 32 + quad * 8];
            f32x4 z = (f32x4){0.f, 0.f, 0.f, 0.f};
            z = __builtin_amdgcn_mfma_f32_16x16x32_bf16(kf0, qf[0], z, 0, 0, 0);
            z = __builtin_amdgcn_mfma_f32_16x16x32_bf16(kf1, qf[1], z, 0, 0, 0);
            s[nf] = z;
        }

        const int jbase = kt * 128 + quad * 4;
        for (int nf = 0; nf < 8; ++nf)
            for (int r = 0; r < 4; ++r) {
                int j = jbase + nf * 16 + r;
                s[nf][r] = s[nf][r] * c1 + slope2 * (float)(j - (T_ - 1));
            }
        if (last) {
            for (int nf = 0; nf < 8; ++nf)
                for (int r = 0; r < 4; ++r)
                    if (jbase + nf * 16 + r > qglob) s[nf][r] = -INFINITY;
        }

        float mx = -INFINITY;
        for (int nf = 0; nf < 8; ++nf) {
            float a = fmaxf(fmaxf(s[nf][0], s[nf][1]), fmaxf(s[nf][2], s[nf][3]));
            mx = fmaxf(mx, a);
        }
        mx = fmaxf(mx, __shfl_xor(mx, 16, 64));
        mx = fmaxf(mx, __shfl_xor(mx, 32, 64));
        const float mnew = fmaxf(m_run, mx);
        const float alpha = exp2f(m_run - mnew);
        m_run = mnew;

        float rs = 0.f;
        bf16x4 pf[8];
        for (int nf = 0; nf < 8; ++nf) {
            float p0 = exp2f(s[nf][0] - mnew);
            float p1 = exp2f(s[nf][1] - mnew);
            float p2 = exp2f(s[nf][2] - mnew);
            float p3 = exp2f(s[nf][3] - mnew);
            rs += (p0 + p1) + (p2 + p3);
            pf[nf] = (bf16x4){(bf16)p0, (bf16)p1, (bf16)p2, (bf16)p3};
        }
        rs += __shfl_xor(rs, 16, 64);
        rs += __shfl_xor(rs, 32, 64);
        l_run = l_run * alpha + rs;
        for (int df = 0; df < 4; ++df) acc[df] *= alpha;

        for (int nf = 0; nf < 8; ++nf)
            for (int df = 0; df < 4; ++df) {
                bf16x4 vf = *(const bf16x4*)&Vs[(df * 16 + l16) * LDP + nf * 16 + quad * 4];
                acc[df] = mfma16x16x16(vf, pf[nf], acc[df]);
            }
    }

    const float inv = 1.0f / l_run;
    const int t = qglob;
    for (int df = 0; df < 4; ++df) {
        bf16 o4[4];
        for (int r = 0; r < 4; ++r) o4[r] = (bf16)(acc[df][r] * inv);
        *(uint2*)&O[(((size_t)b * T_ + t) * H_ + h) * HD + df * 16 + quad * 4] =
            *(const uint2*)o4;
    }
}

// ---------------------------------------------------------------- launch
extern "C" void kernel_launch(void* const* d_in, const int* in_sizes, int n_in,
                              void* d_out, int out_size, void* d_ws, size_t ws_size,
                              hipStream_t stream) {
    const float* x  = (const float*)d_in[0];
    const float* Wq = (const float*)d_in[1];
    const float* Wk = (const float*)d_in[2];
    const float* Wv = (const float*)d_in[3];
    const float* Wo = (const float*)d_in[4];
    float* out = (float*)d_out;

    const size_t M = (size_t)B_ * T_;        // 4096
    const size_t XE = M * D_;                // 4 Mi elems
    const size_t WE = (size_t)D_ * D_;       // 1 Mi elems

    char* ws = (char*)d_ws;
    size_t off = 0;
    auto carve = [&](size_t bytes) {
        void* p = ws + off;
        off += (bytes + 255) & ~(size_t)255;
        return p;
    };
    bf16* xb  = (bf16*)carve(XE * 2);        // x bf16; reused as attn_out later
    bf16* Wt  = (bf16*)carve(4 * WE * 2);    // Wq,Wk,Wv,Wo transposed [N][K]
    bf16* QKV = (bf16*)carve(3 * XE * 2);    // Q,K [B,H,T,hd]; V [B,H,hd,T]
    bf16* attn = xb;  // safe: xb fully consumed by QKV gemm before attn_kernel runs

    cast_f32_bf16<<<dim3(XE / (4 * 256)), dim3(256), 0, stream>>>(x, xb, (int)XE);
    transpose_cast4<<<dim3(16, 16, 4), 256, 0, stream>>>(Wq, Wk, Wv, Wo, Wt);

    gemm_bf16<<<dim3(D_ / 128, M / 128, 3), 256, 0, stream>>>(xb, Wt, QKV,
                                                              (int)M, D_, D_, 0);
    attn_kernel<<<dim3(32, B_ * H_), 256, 0, stream>>>(QKV, QKV + XE, QKV + 2 * XE, attn);
    gemm_bf16<<<dim3(D_ / 128, M / 128, 1), 256, 0, stream>>>(attn, Wt + 3 * WE, out,
                                                              (int)M, D_, D_, 1);
}